// Round 1
// baseline (158.399 us; speedup 1.0000x reference)
//
#include <hip/hip_runtime.h>
#include <hip/hip_bf16.h>

#define NEXP 16
#define KDIM 1024
#define ODIM 4096
#define NTOK 2048

#define BM 256
#define BN 64
#define BK 32
#define KITERS (KDIM / BK)   // 32

typedef __attribute__((ext_vector_type(8))) short short8;
typedef __attribute__((ext_vector_type(4))) float f32x4;

__device__ __forceinline__ unsigned short f2bf(float f) {
    __hip_bfloat16 h = __float2bfloat16(f);
    return __builtin_bit_cast(unsigned short, h);
}

__device__ __forceinline__ short8 pack8(float4 a, float4 b) {
    short8 r;
    r[0] = (short)f2bf(a.x); r[1] = (short)f2bf(a.y);
    r[2] = (short)f2bf(a.z); r[3] = (short)f2bf(a.w);
    r[4] = (short)f2bf(b.x); r[5] = (short)f2bf(b.y);
    r[6] = (short)f2bf(b.z); r[7] = (short)f2bf(b.w);
    return r;
}

// ---------------------------------------------------------------------------
// Kernel 1: deterministic counting sort of tokens by expert.
// perm[pos] = token id, grouped by expert, stable by token id (no atomics).
// offs[e]..offs[e+1] = range of expert e in perm. Single block, 256 threads.
// ---------------------------------------------------------------------------
__global__ __launch_bounds__(256) void moe_sort(const int* __restrict__ gate,
                                                int* __restrict__ perm,
                                                int* __restrict__ offs) {
    __shared__ int lgate[NTOK];          // 8 KB
    __shared__ int hist[256][NEXP];      // 16 KB
    __shared__ int base[NEXP];
    const int t = threadIdx.x;
    for (int i = t; i < NTOK; i += 256) lgate[i] = gate[i];
    #pragma unroll
    for (int e = 0; e < NEXP; ++e) hist[t][e] = 0;
    __syncthreads();
    const int TPT = NTOK / 256;          // 8 tokens per thread
    for (int j = 0; j < TPT; ++j) hist[t][lgate[t * TPT + j]]++;
    __syncthreads();
    if (t < NEXP) {                      // exclusive scan over threads, per expert
        int s = 0;
        for (int i = 0; i < 256; ++i) { int v = hist[i][t]; hist[i][t] = s; s += v; }
        base[t] = s;                     // total for expert t (temporarily)
    }
    __syncthreads();
    if (t == 0) {                        // exclusive scan over experts
        int s = 0;
        for (int e = 0; e < NEXP; ++e) { int v = base[e]; base[e] = s; offs[e] = s; s += v; }
        offs[NEXP] = s;
    }
    __syncthreads();
    #pragma unroll
    for (int e = 0; e < NEXP; ++e) hist[t][e] += base[e];
    for (int j = 0; j < TPT; ++j) {
        int tok = t * TPT + j;
        int e = lgate[tok];
        int pos = hist[t][e]++;
        perm[pos] = tok;
    }
}

// ---------------------------------------------------------------------------
// Kernel 2: grouped GEMM. Block = (expert z, out-tile x of 64, token-chunk y
// of 256). out[perm[r], oc+n] = sum_k inp[perm[r], k] * W[e, oc+n, k],
// bf16 MFMA 16x16x32, fp32 accumulate in registers across the whole K loop.
// LDS layout is k-slot-major: As[buf][ks][row][8] so that both staging
// ds_write_b128 and fragment ds_read_b128 are bank-conflict-free.
// ---------------------------------------------------------------------------
__global__ __launch_bounds__(256, 3) void moe_gemm(
    const float* __restrict__ inp,
    const float* __restrict__ weight,
    const int* __restrict__ perm,
    const int* __restrict__ offs,
    float* __restrict__ out)
{
    const int e   = blockIdx.z;
    const int oc  = blockIdx.x * BN;
    const int beg = offs[e], end = offs[e + 1];
    const int chunk0 = beg + blockIdx.y * BM;
    if (chunk0 >= end) return;           // empty chunk: block-uniform exit
    int rows = end - chunk0; if (rows > BM) rows = BM;

    __shared__ short As[2][4][BM][8];    // 32 KB  (bf16 bits)
    __shared__ short Bs[2][4][BN][8];    //  8 KB

    const int t    = threadIdx.x;
    const int lane = t & 63;
    const int w    = t >> 6;             // wave id; doubles as staging k-slot

    // ---- staging source pointers ----
    // A: this thread stages rows {lane + 64*rep}, k-slot w (8 floats).
    const float* aptr[4];
    bool avalid[4];
    #pragma unroll
    for (int rep = 0; rep < 4; ++rep) {
        int r = rep * 64 + lane;
        avalid[rep] = (r < rows);
        int tok = avalid[rep] ? perm[chunk0 + r] : 0;
        aptr[rep] = inp + (size_t)tok * KDIM + w * 8;
    }
    // B: this thread stages weight row (oc+lane), k-slot w.
    const float* bptr = weight + ((size_t)e * ODIM + oc + lane) * KDIM + w * 8;

    float4 a0[4], a1[4], b0, b1;         // in-flight staging registers
    f32x4 acc[4][4];
    #pragma unroll
    for (int m = 0; m < 4; ++m)
        #pragma unroll
        for (int n = 0; n < 4; ++n)
            acc[m][n] = (f32x4){0.f, 0.f, 0.f, 0.f};

    const bool wactive = (w * 64) < rows;   // this wave's M-slab has real rows
    const int  frow = lane & 15;            // fragment row/col within 16
    const int  fks  = lane >> 4;            // fragment k-slot (k = fks*8 + j)

    auto LOADG = [&](int kk) {
        #pragma unroll
        for (int rep = 0; rep < 4; ++rep) {
            if (avalid[rep]) {
                a0[rep] = *(const float4*)(aptr[rep] + kk);
                a1[rep] = *(const float4*)(aptr[rep] + kk + 4);
            }
        }
        b0 = *(const float4*)(bptr + kk);
        b1 = *(const float4*)(bptr + kk + 4);
    };
    auto CVTWRITE = [&](int buf) {
        #pragma unroll
        for (int rep = 0; rep < 4; ++rep) {
            if (avalid[rep]) {
                *(short8*)(&As[buf][w][rep * 64 + lane][0]) = pack8(a0[rep], a1[rep]);
            }
        }
        *(short8*)(&Bs[buf][w][lane][0]) = pack8(b0, b1);
    };
    auto COMPUTE = [&](int buf) {
        if (!wactive) return;            // no barrier inside: safe wave-uniform skip
        short8 bf[4];
        #pragma unroll
        for (int n = 0; n < 4; ++n)
            bf[n] = *(const short8*)(&Bs[buf][fks][n * 16 + frow][0]);
        #pragma unroll
        for (int m = 0; m < 4; ++m) {
            short8 af = *(const short8*)(&As[buf][fks][w * 64 + m * 16 + frow][0]);
            #pragma unroll
            for (int n = 0; n < 4; ++n)
                acc[m][n] = __builtin_amdgcn_mfma_f32_16x16x32_bf16(af, bf[n], acc[m][n], 0, 0, 0);
        }
    };

    // ---- main loop: 32 K-steps, double-buffered, one barrier per step ----
    LOADG(0);
    CVTWRITE(0);
    __syncthreads();
    int cur = 0;
    for (int it = 0; it < KITERS - 1; ++it) {
        LOADG((it + 1) * BK);            // issue next-tile loads early
        COMPUTE(cur);                    // MFMAs hide the load latency
        CVTWRITE(cur ^ 1);               // vmcnt wait happens here, post-MFMA
        __syncthreads();
        cur ^= 1;
    }
    COMPUTE(cur);

    // ---- epilogue: C layout col=lane&15, row=(lane>>4)*4+reg (verified) ----
    if (wactive) {
        const int col0  = oc + frow;
        const int rbase = w * 64 + (lane >> 4) * 4;
        #pragma unroll
        for (int m = 0; m < 4; ++m) {
            #pragma unroll
            for (int reg = 0; reg < 4; ++reg) {
                int r = rbase + m * 16 + reg;
                if (r < rows) {
                    int tok = perm[chunk0 + r];
                    float* orow = out + (size_t)tok * ODIM + col0;
                    #pragma unroll
                    for (int n = 0; n < 4; ++n)
                        orow[n * 16] = acc[m][n][reg];
                }
            }
        }
    }
}

extern "C" void kernel_launch(void* const* d_in, const int* in_sizes, int n_in,
                              void* d_out, int out_size, void* d_ws, size_t ws_size,
                              hipStream_t stream) {
    const float* inp    = (const float*)d_in[0];
    const int*   gate   = (const int*)d_in[1];
    const float* weight = (const float*)d_in[2];
    float*       out    = (float*)d_out;

    int* perm = (int*)d_ws;              // 2048 ints
    int* offs = perm + NTOK;             // 17 ints

    moe_sort<<<1, 256, 0, stream>>>(gate, perm, offs);

    dim3 grid(ODIM / BN, NTOK / BM, NEXP);   // 64 x 8 x 16 (most y>0 exit)
    moe_gemm<<<grid, 256, 0, stream>>>(inp, weight, perm, offs, out);
}

// Round 2
// 133.747 us; speedup vs baseline: 1.1843x; 1.1843x over previous
//
#include <hip/hip_runtime.h>
#include <hip/hip_bf16.h>

#define NEXP 16
#define KDIM 1024
#define ODIM 4096
#define NTOK 2048

#define BM 128
#define BN 64
#define BK 64
#define NCH 2                       // max token-chunks per expert (n_e <= 256)
#define KIT (KDIM / BK)             // 16
#define NBLK (NEXP * (ODIM / BN) * NCH)   // 2048

typedef __attribute__((ext_vector_type(8))) short short8;
typedef __attribute__((ext_vector_type(4))) float f32x4;

__device__ __forceinline__ unsigned short f2bf(float f) {
    __hip_bfloat16 h = __float2bfloat16(f);
    return __builtin_bit_cast(unsigned short, h);
}

__device__ __forceinline__ short8 pack8(float4 a, float4 b) {
    short8 r;
    r[0] = (short)f2bf(a.x); r[1] = (short)f2bf(a.y);
    r[2] = (short)f2bf(a.z); r[3] = (short)f2bf(a.w);
    r[4] = (short)f2bf(b.x); r[5] = (short)f2bf(b.y);
    r[6] = (short)f2bf(b.z); r[7] = (short)f2bf(b.w);
    return r;
}

// ---------------------------------------------------------------------------
// Kernel 1: deterministic counting sort of tokens by expert (unchanged).
// ---------------------------------------------------------------------------
__global__ __launch_bounds__(256) void moe_sort(const int* __restrict__ gate,
                                                int* __restrict__ perm,
                                                int* __restrict__ offs) {
    __shared__ int lgate[NTOK];
    __shared__ int hist[256][NEXP];
    __shared__ int base[NEXP];
    const int t = threadIdx.x;
    for (int i = t; i < NTOK; i += 256) lgate[i] = gate[i];
    #pragma unroll
    for (int e = 0; e < NEXP; ++e) hist[t][e] = 0;
    __syncthreads();
    const int TPT = NTOK / 256;
    for (int j = 0; j < TPT; ++j) hist[t][lgate[t * TPT + j]]++;
    __syncthreads();
    if (t < NEXP) {
        int s = 0;
        for (int i = 0; i < 256; ++i) { int v = hist[i][t]; hist[i][t] = s; s += v; }
        base[t] = s;
    }
    __syncthreads();
    if (t == 0) {
        int s = 0;
        for (int e = 0; e < NEXP; ++e) { int v = base[e]; base[e] = s; offs[e] = s; s += v; }
        offs[NEXP] = s;
    }
    __syncthreads();
    #pragma unroll
    for (int e = 0; e < NEXP; ++e) hist[t][e] += base[e];
    for (int j = 0; j < TPT; ++j) {
        int tok = t * TPT + j;
        int e = lgate[tok];
        int pos = hist[t][e]++;
        perm[pos] = tok;
    }
}

// ---------------------------------------------------------------------------
// Kernel 2: grouped GEMM, coalesced staging.
// Staging map: thread t owns k-octet (t&7) of rows {t>>3 (+32,+64,+96)} —
// 8 consecutive threads read 256B contiguous of one row (8 fully-used 128B
// segments per wave-instruction, vs 64 sparse segments in R1).
// LDS is k-octet-major [oct][row][8] -> ds_read_b128 fragments conflict-free
// (measured 0 conflicts in R1).
// XCD swizzle: blockIdx%8 -> XCD; give each XCD a contiguous 256-block span
// = 2 experts, so A-rows for those experts stay resident in that XCD's L2.
// ---------------------------------------------------------------------------
__global__ __launch_bounds__(256, 3) void moe_gemm(
    const float* __restrict__ inp,
    const float* __restrict__ weight,
    const int* __restrict__ perm,
    const int* __restrict__ offs,
    float* __restrict__ out)
{
    const int bid = blockIdx.x;
    const int v   = (bid & 7) * (NBLK / 8) + (bid >> 3);   // XCD-contiguous remap
    const int e   = v >> 7;            // 128 blocks per expert
    const int rem = v & 127;
    const int oc  = (rem >> 1) * BN;
    const int ch  = rem & 1;

    const int beg = offs[e], end = offs[e + 1];
    const int chunk0 = beg + ch * BM;
    if (chunk0 >= end) return;
    int rows = end - chunk0; if (rows > BM) rows = BM;

    __shared__ short As[2][8][BM][8];   // 32 KB: [buf][k-octet][row][8 bf16]
    __shared__ short Bs[2][8][BN][8];   // 16 KB

    const int t    = threadIdx.x;
    const int lane = t & 63;
    const int w    = t >> 6;
    const int wm   = w >> 1;            // wave row-half  (0..1)
    const int wn   = w & 1;             // wave col-half  (0..1)

    // ---- staging map ----
    const int oct = t & 7;              // k-octet within the BK=64 tile
    const int rr  = t >> 3;             // base row 0..31

    const float* aptr[4]; bool avalid[4];
    #pragma unroll
    for (int rep = 0; rep < 4; ++rep) {
        int r = rr + 32 * rep;
        avalid[rep] = (r < rows);
        int tok = avalid[rep] ? perm[chunk0 + r] : 0;
        aptr[rep] = inp + (size_t)tok * KDIM + oct * 8;
    }
    const float* bptr0 = weight + ((size_t)e * ODIM + oc + rr) * KDIM + oct * 8;
    const float* bptr1 = bptr0 + (size_t)32 * KDIM;

    float4 a0[4], a1[4], b0[2], b1[2];
    f32x4 acc[4][2];
    #pragma unroll
    for (int m = 0; m < 4; ++m)
        #pragma unroll
        for (int n = 0; n < 2; ++n)
            acc[m][n] = (f32x4){0.f, 0.f, 0.f, 0.f};

    const bool wactive = (wm * 64) < rows;
    const int  frow = lane & 15;
    const int  fks  = lane >> 4;

    auto LOADG = [&](int kk) {
        #pragma unroll
        for (int rep = 0; rep < 4; ++rep) {
            if (avalid[rep]) {
                a0[rep] = *(const float4*)(aptr[rep] + kk);
                a1[rep] = *(const float4*)(aptr[rep] + kk + 4);
            }
        }
        b0[0] = *(const float4*)(bptr0 + kk);
        b1[0] = *(const float4*)(bptr0 + kk + 4);
        b0[1] = *(const float4*)(bptr1 + kk);
        b1[1] = *(const float4*)(bptr1 + kk + 4);
    };
    auto CVTWRITE = [&](int buf) {
        #pragma unroll
        for (int rep = 0; rep < 4; ++rep)
            if (avalid[rep])
                *(short8*)(&As[buf][oct][rr + 32 * rep][0]) = pack8(a0[rep], a1[rep]);
        *(short8*)(&Bs[buf][oct][rr][0])      = pack8(b0[0], b1[0]);
        *(short8*)(&Bs[buf][oct][rr + 32][0]) = pack8(b0[1], b1[1]);
    };
    auto COMPUTE = [&](int buf) {
        if (!wactive) return;           // wave-uniform skip, no barrier inside
        short8 bf[2][2];
        #pragma unroll
        for (int kk = 0; kk < 2; ++kk)
            #pragma unroll
            for (int n = 0; n < 2; ++n)
                bf[kk][n] = *(const short8*)(&Bs[buf][kk * 4 + fks][wn * 32 + n * 16 + frow][0]);
        #pragma unroll
        for (int kk = 0; kk < 2; ++kk)
            #pragma unroll
            for (int m = 0; m < 4; ++m) {
                short8 af = *(const short8*)(&As[buf][kk * 4 + fks][wm * 64 + m * 16 + frow][0]);
                #pragma unroll
                for (int n = 0; n < 2; ++n)
                    acc[m][n] = __builtin_amdgcn_mfma_f32_16x16x32_bf16(af, bf[kk][n], acc[m][n], 0, 0, 0);
            }
    };

    // ---- main loop: 16 K-steps, double-buffered, one barrier per step ----
    LOADG(0);
    CVTWRITE(0);
    __syncthreads();
    int cur = 0;
    for (int it = 0; it < KIT - 1; ++it) {
        LOADG((it + 1) * BK);           // issue next-tile loads early
        COMPUTE(cur);                   // MFMAs hide load latency
        CVTWRITE(cur ^ 1);              // vmcnt wait lands here, post-MFMA
        __syncthreads();
        cur ^= 1;
    }
    COMPUTE(cur);

    // ---- epilogue: C layout col=lane&15, row=(lane>>4)*4+reg ----
    if (wactive) {
        const int col0  = oc + wn * 32 + frow;
        const int rbase = wm * 64 + fks * 4;
        #pragma unroll
        for (int m = 0; m < 4; ++m) {
            #pragma unroll
            for (int reg = 0; reg < 4; ++reg) {
                int r = rbase + m * 16 + reg;
                if (r < rows) {
                    int tok = perm[chunk0 + r];
                    float* orow = out + (size_t)tok * ODIM + col0;
                    #pragma unroll
                    for (int n = 0; n < 2; ++n)
                        orow[n * 16] = acc[m][n][reg];
                }
            }
        }
    }
}

extern "C" void kernel_launch(void* const* d_in, const int* in_sizes, int n_in,
                              void* d_out, int out_size, void* d_ws, size_t ws_size,
                              hipStream_t stream) {
    const float* inp    = (const float*)d_in[0];
    const int*   gate   = (const int*)d_in[1];
    const float* weight = (const float*)d_in[2];
    float*       out    = (float*)d_out;

    int* perm = (int*)d_ws;
    int* offs = perm + NTOK;

    moe_sort<<<1, 256, 0, stream>>>(gate, perm, offs);
    moe_gemm<<<NBLK, 256, 0, stream>>>(inp, weight, perm, offs, out);
}